// Round 6
// baseline (767.071 us; speedup 1.0000x reference)
//
#include <hip/hip_runtime.h>
#include <stdint.h>

#define HW 16384
#define CDIM 768
#define KB32 (CDIM / 32)       // 24 k-blocks per row-block
#define EPSF 1e-8f

typedef float f32x4 __attribute__((ext_vector_type(4)));

__device__ inline uint32_t pk4_fp8(float v0, float v1, float v2, float v3) {
    uint32_t r = __builtin_amdgcn_cvt_pk_fp8_f32(v0, v1, 0, false);
    r = __builtin_amdgcn_cvt_pk_fp8_f32(v2, v3, r, true);
    return r;   // bytes [v0,v1,v2,v3] little-endian
}

// ---- Kernel 1: transpose [C][HW] fp32 -> fragment-tiled fp8 + column sum-sq ----
// Output layout: 16-row x 32-k tiles of 512 B; byte(row r, k=q*8+o) at
// tile*512 + (q*16+r)*8 + o. A wave's MFMA frag load is then ONE coalesced
// dwordx2 at tile_base + lane*8 (lane = q*16+r) -> the GEMM needs no LDS.
// z=0: a (scale x16), z=1: b (scale x8, raw; normalization in GEMM epilogue).
__global__ void __launch_bounds__(256)
transpose_fp8_norm(const float* __restrict__ a, const float* __restrict__ b,
                   uint8_t* __restrict__ at8, uint8_t* __restrict__ bn8,
                   float* __restrict__ sumsq_a, float* __restrict__ sumsq_b) {
    const int z = blockIdx.z;
    const float* src = z ? b : a;
    uint32_t* dst32 = (uint32_t*)(z ? bn8 : at8);
    float* sums = z ? sumsq_b : sumsq_a;
    const float mult = z ? 8.0f : 16.0f;

    __shared__ float tile[64][65];   // [channel][spatial], +1 pad
    __shared__ float red[4][64];
    const int s0 = blockIdx.x * 64, c0 = blockIdx.y * 64;
    const int tx = threadIdx.x & 63, ty = threadIdx.x >> 6;

    float part = 0.f;
#pragma unroll
    for (int p = 0; p < 16; ++p) {
        int cl = p * 4 + ty;
        float v = src[(size_t)(c0 + cl) * HW + s0 + tx];
        tile[cl][tx] = v;
        part = fmaf(v, v, part);     // per-spatial-column partial sum-sq
    }
    red[ty][tx] = part;
    __syncthreads();
    if (ty == 0)
        atomicAdd(&sums[s0 + tx], red[0][tx] + red[1][tx] + red[2][tx] + red[3][tx]);

    // write phase: 1024 u32 per block, fully coalesced into 512 B tiles
    const int t = threadIdx.x;
#pragma unroll
    for (int p = 0; p < 4; ++p) {
        int id   = p * 256 + t;      // 0..1023
        int rblk = id >> 8;          // spatial row-block within s-tile (0..3)
        int rest = id & 255;
        int kb   = rest >> 7;        // k-block within c-tile (0..1)
        int lane = (rest & 127) >> 1;
        int half = rest & 1;
        int r    = lane & 15;        // row within 16-row block
        int q    = lane >> 4;        // k-quad
        int ch   = kb * 32 + q * 8 + half * 4;   // channel offset in c-tile
        int row  = rblk * 16 + r;                // spatial row in s-tile
        float v0 = tile[ch + 0][row], v1 = tile[ch + 1][row];
        float v2 = tile[ch + 2][row], v3 = tile[ch + 3][row];
        size_t off32 = ((size_t)((s0 >> 4) + rblk) * KB32 + (c0 >> 5) + kb) * 128
                     + lane * 2 + half;
        dst32[off32] = pk4_fp8(v0 * mult, v1 * mult, v2 * mult, v3 * mult);
    }
}

// ---- Kernel 2: LDS-free fp8 GEMM + normalize + argmax epilogue ----
// 128x128 tile, 4 waves (2x2), 4x4 frags of mfma_f32_16x16x32_fp8_fp8.
// No __shared__, no __syncthreads in the K-loop: fragments load directly
// global->VGPR (coalesced dwordx2 from the fragment-tiled layout), so there
// is no vmcnt(0) barrier drain — the compiler software-pipelines loads with
// fine-grained vmcnt across the fully unrolled K-loop (round-5 analysis:
// true MFMA util was ~10%, the 2-barrier drain was the limiter, not BW).
// Cost: 2x operand L2 traffic (wave-level duplication) — ~33 B/cyc/CU of a
// ~56 B/cyc share at target speed; co-resident supertile blocks share jt so
// B lines hit L1. XCD swizzle: blockIdx%8 = XCD; 4x8-tile supertiles.
__global__ void __launch_bounds__(256, 4)
gemm_argmax(const uint8_t* __restrict__ at8, const uint8_t* __restrict__ bn8,
            const float* __restrict__ sumsq_b,
            unsigned long long* __restrict__ best) {
    const int g = blockIdx.x;          // 0..16383
    const int xcd    = g & 7;
    const int s      = g >> 3;
    const int super  = s >> 5;         // 32 blocks / supertile
    const int within = s & 31;
    const int si = super >> 4;         // 4 i-tiles per supertile row
    const int sj = super & 15;         // 8 j-tiles per supertile col
    const int it = xcd * 16 + si * 4 + (within & 3);
    const int jt = sj * 8 + (within >> 2);

    const int i0 = it * 128, j0 = jt * 128;
    const int tid = threadIdx.x;
    const int lane = tid & 63, w = tid >> 6;
    const int wi = w & 1, wj = w >> 1;
    const int quad = lane >> 4, l15 = lane & 15;

    f32x4 acc[4][4] = {};

    // frag bases: row-block rb -> rb*KB32*512; this wave's first rb + lane slot
    const uint8_t* aB = at8 + ((size_t)((i0 >> 4) + wi * 4) * KB32) * 512 + lane * 8;
    const uint8_t* bB = bn8 + ((size_t)((j0 >> 4) + wj * 4) * KB32) * 512 + lane * 8;

#pragma unroll
    for (int kb = 0; kb < KB32; ++kb) {
        long af[4], bg[4];
#pragma unroll
        for (int m = 0; m < 4; ++m)
            af[m] = *(const long*)(aB + ((size_t)m * KB32 + kb) * 512);
#pragma unroll
        for (int n = 0; n < 4; ++n)
            bg[n] = *(const long*)(bB + ((size_t)n * KB32 + kb) * 512);
#pragma unroll
        for (int m = 0; m < 4; ++m)
#pragma unroll
            for (int n = 0; n < 4; ++n)
                acc[m][n] = __builtin_amdgcn_mfma_f32_16x16x32_fp8_fp8(
                    af[m], bg[n], acc[m][n], 0, 0, 0);
    }

    // epilogue: normalize by per-j denom, then argmax over this block's j's
    float invd[4];
#pragma unroll
    for (int n = 0; n < 4; ++n) {
        float sq = sumsq_b[j0 + wj * 64 + n * 16 + l15];
        invd[n] = 1.0f / (sqrtf(sq + EPSF) + EPSF);
    }
#pragma unroll
    for (int m = 0; m < 4; ++m) {
#pragma unroll
        for (int r = 0; r < 4; ++r) {
            float v = acc[m][0][r] * invd[0];
            int j = j0 + wj * 64 + l15;
#pragma unroll
            for (int n = 1; n < 4; ++n) {
                float vn = acc[m][n][r] * invd[n];
                int jn = j0 + wj * 64 + n * 16 + l15;
                if (vn > v) { v = vn; j = jn; }   // strict >: keeps smallest j
            }
#pragma unroll
            for (int msk = 1; msk < 16; msk <<= 1) {
                float ov = __shfl_xor(v, msk, 64);
                int   oj = __shfl_xor(j, msk, 64);
                if (ov > v || (ov == v && oj < j)) { v = ov; j = oj; }
            }
            if (l15 == 0) {
                int gi = i0 + wi * 64 + m * 16 + quad * 4 + r;
                uint32_t u = __float_as_uint(v);
                u = (u & 0x80000000u) ? ~u : (u | 0x80000000u);  // orderable f32
                unsigned long long packed =
                    ((unsigned long long)u << 32) | (uint32_t)(~(uint32_t)j);
                atomicMax(&best[gi], packed);  // ties -> larger ~j -> smaller j
            }
        }
    }
}

// ---- Kernel 3: final loss from stored argmax dot (no gather) ----
// stored v = 128 * dot(a_i, b_j) / denom_b[j]  (fp8 dot, fp32 denom)
__global__ void loss_reduce(const unsigned long long* __restrict__ best,
                            const float* __restrict__ sumsq_a,
                            const float* __restrict__ sumsq_b,
                            float* __restrict__ out) {
    int i = blockIdx.x * 256 + threadIdx.x;
    unsigned long long pk = best[i];
    uint32_t x = (uint32_t)(pk >> 32);
    float v = (x & 0x80000000u) ? __uint_as_float(x & 0x7fffffffu)
                                : __uint_as_float(~x);
    int j = (int)(~(uint32_t)pk);
    float sb = sumsq_b[j];
    float denb = sqrtf(sb + EPSF) + EPSF;
    float dot = v * denb * (1.0f / 128.0f);
    float cs = dot / ((sqrtf(sumsq_a[i]) + EPSF) * (sqrtf(sb) + EPSF));
    float term = 1.0f - cs;
#pragma unroll
    for (int m = 32; m; m >>= 1) term += __shfl_down(term, m, 64);
    __shared__ float red[4];
    int wv = threadIdx.x >> 6, lane = threadIdx.x & 63;
    if (lane == 0) red[wv] = term;
    __syncthreads();
    if (threadIdx.x == 0) {
        float ssum = (red[0] + red[1] + red[2] + red[3]) * (1.0f / HW);
        atomicAdd(out, ssum);
    }
}

extern "C" void kernel_launch(void* const* d_in, const int* in_sizes, int n_in,
                              void* d_out, int out_size, void* d_ws, size_t ws_size,
                              hipStream_t stream) {
    const float* a = (const float*)d_in[0];
    const float* b = (const float*)d_in[1];
    char* ws = (char*)d_ws;

    const size_t T_BYTES = (size_t)HW * CDIM;   // 12.58 MB per fp8 matrix
    uint8_t* at8 = (uint8_t*)ws;
    uint8_t* bn8 = (uint8_t*)(ws + T_BYTES);
    float* sumsq_a = (float*)(ws + 2 * T_BYTES);
    float* sumsq_b = (float*)(ws + 2 * T_BYTES + HW * sizeof(float));
    unsigned long long* best =
        (unsigned long long*)(ws + 2 * T_BYTES + 2 * HW * sizeof(float));

    // zero sumsq_a + sumsq_b + best in one contiguous memset
    hipMemsetAsync(sumsq_a, 0, 2 * HW * sizeof(float) + HW * sizeof(unsigned long long),
                   stream);
    hipMemsetAsync(d_out, 0, out_size * sizeof(float), stream);

    dim3 tg(HW / 64, CDIM / 64, 2);
    transpose_fp8_norm<<<tg, 256, 0, stream>>>(a, b, at8, bn8, sumsq_a, sumsq_b);
    gemm_argmax<<<(HW / 128) * (HW / 128), 256, 0, stream>>>(at8, bn8, sumsq_b, best);
    loss_reduce<<<HW / 256, 256, 0, stream>>>(best, sumsq_a, sumsq_b, (float*)d_out);
}